// Round 18
// baseline (297.811 us; speedup 1.0000x reference)
//
#include <hip/hip_runtime.h>
#include <hip/hip_cooperative_groups.h>
#include <math.h>

namespace cg = cooperative_groups;

#define NMS_THR 0.3f
#define NACC 8            // accumulator waves in scan phase (block = 576 thr)
#define NBLK 256          // 1 block per CU, co-resident for cooperative launch
#define NTHR 576          // 9 waves

__device__ __forceinline__ float fmul(float a, float b){ return __fmul_rn(a,b); }
__device__ __forceinline__ float fadd(float a, float b){ return __fadd_rn(a,b); }
__device__ __forceinline__ float fsub(float a, float b){ return __fsub_rn(a,b); }

// Raw barrier: LDS ordering only — does NOT drain vmcnt.
#define BAR_LDS() asm volatile("s_waitcnt lgkmcnt(0)\n\ts_barrier" ::: "memory")

__device__ __forceinline__ unsigned long long rfl64(unsigned long long x){
    unsigned int lo = (unsigned int)__builtin_amdgcn_readfirstlane((int)(unsigned int)x);
    unsigned int hi = (unsigned int)__builtin_amdgcn_readfirstlane((int)(unsigned int)(x >> 32));
    return ((unsigned long long)hi << 32) | lo;
}

struct Params {
    const float *prop, *reg, *clss, *stds;
    const int *img;
    float *boxes, *key, *score;
    int *cls, *rank;
    float *boxesSorted, *areaSorted, *keySorted;
    int *keepSorted, *nValid;
    unsigned long long *bq, *mask;
    float *out;
    int N, C, W, Wpad, rankBlocks;
};

__global__ __launch_bounds__(NTHR, 1) void k_all(Params p)
{
    cg::grid_group grid = cg::this_grid();
    extern __shared__ char smem[];
    const int tid  = threadIdx.x;
    const int bid  = blockIdx.x;
    const int wi   = tid >> 6;          // wave in block, 0..8
    const int lane = tid & 63;
    const int gwave  = bid * (NTHR/64) + wi;
    const int nWaves = gridDim.x * (NTHR/64);
    const int N = p.N, C = p.C, W = p.W, Wpad = p.Wpad;
    const float ninf = -__builtin_inff();

    // ---------------- Phase 1: decode (one wave per row, grid-stride) -------
    for (int n = gwave; n < N; n += nWaves) {
        const float* row = p.clss + (long)n * C;
        float x0 = (lane < C)      ? row[lane]      : ninf;
        float x1 = (lane + 64 < C) ? row[lane + 64] : ninf;
        float m = fmaxf(x0, x1);
        for (int o = 32; o > 0; o >>= 1) m = fmaxf(m, __shfl_xor(m, o));
        float e0 = (lane < C)      ? expf(x0 - m) : 0.0f;
        float e1 = (lane + 64 < C) ? expf(x1 - m) : 0.0f;
        float s = e0 + e1;
        for (int o = 32; o > 0; o >>= 1) s += __shfl_xor(s, o);
        float bv; int bi;
        if (e0 >= e1) { bv = e0; bi = lane; } else { bv = e1; bi = lane + 64; }
        for (int o = 32; o > 0; o >>= 1) {
            float ov = __shfl_xor(bv, o);
            int   oi = __shfl_xor(bi, o);
            if (ov > bv || (ov == bv && oi < bi)) { bv = ov; bi = oi; }
        }
        if (lane == 0) {
            float sc = 1.0f / s;
            int   c  = bi;
            int   valid = (c != 0);
            float p0 = p.prop[n*4+0], p1 = p.prop[n*4+1];
            float p2 = p.prop[n*4+2], p3 = p.prop[n*4+3];
            float w  = fsub(p2, p0), h = fsub(p3, p1);
            float cx = fadd(p0, fmul(0.5f, w));
            float cy = fadd(p1, fmul(0.5f, h));
            const float* rr = p.reg + (long)n * C * 4 + (long)c * 4;
            float t0 = fmul(rr[0], p.stds[0]);
            float t1 = fmul(rr[1], p.stds[1]);
            float t2 = fmul(rr[2], p.stds[2]);
            float t3 = fmul(rr[3], p.stds[3]);
            float px = fadd(cx, fmul(w, t0));
            float py = fadd(cy, fmul(h, t1));
            float pw = fmul(w, expf(t2));
            float ph = fmul(h, expf(t3));
            float hi = (float)(p.img[0] - 1);
            float bx1 = fminf(fmaxf(fsub(px, fmul(0.5f, pw)), 0.0f), hi);
            float by1 = fminf(fmaxf(fsub(py, fmul(0.5f, ph)), 0.0f), hi);
            float bx2 = fminf(fmaxf(fadd(px, fmul(0.5f, pw)), 0.0f), hi);
            float by2 = fminf(fmaxf(fadd(py, fmul(0.5f, ph)), 0.0f), hi);
            p.boxes[n*4+0]=bx1; p.boxes[n*4+1]=by1;
            p.boxes[n*4+2]=bx2; p.boxes[n*4+3]=by2;
            p.score[n] = sc;
            p.cls[n]   = c;
            p.key[n]   = valid ? sc : ninf;
        }
    }
    grid.sync();

    // ---------------- Phase 2: stable rank sort (blocks < rankBlocks) -------
    {
        float* lkey = (float*)smem;                       // N floats
        int*   part = (int*)(smem + (size_t)N*sizeof(float)); // NTHR ints
        if (bid < p.rankBlocks) {
            for (int j = tid; j < N; j += NTHR) lkey[j] = p.key[j];
            __syncthreads();
            int i = bid * 64 + lane;
            int Q = (N + 8) / 9;
            int r_part = 0;
            if (i < N) {
                float ki = lkey[i];
                int j0 = wi * Q, j1 = min(N, j0 + Q);
                for (int j = j0; j < j1; ++j) {
                    float kj = lkey[j];
                    r_part += (kj > ki) || (kj == ki && j < i);   // stable
                }
            }
            part[tid] = r_part;
            __syncthreads();
            if (tid < 64 && i < N) {
                int r = 0;
#pragma unroll
                for (int sIdx = 0; sIdx < 9; ++sIdx) r += part[tid + 64*sIdx];
                float ki = lkey[i];
                p.rank[i] = r;
                float b0 = p.boxes[i*4+0], b1 = p.boxes[i*4+1];
                float b2 = p.boxes[i*4+2], b3 = p.boxes[i*4+3];
                p.boxesSorted[r*4+0]=b0; p.boxesSorted[r*4+1]=b1;
                p.boxesSorted[r*4+2]=b2; p.boxesSorted[r*4+3]=b3;
                p.areaSorted[r] = fmul(fsub(b2,b0), fsub(b3,b1));
                p.keySorted[r]  = ki;
            }
            if (bid == 0) {
                __syncthreads();
                int inv = 0;
                for (int j = tid; j < N; j += NTHR) inv += (lkey[j] == ninf);
                part[tid] = inv;
                __syncthreads();
                if (tid == 0) {
                    int t = 0;
                    for (int q = 0; q < NTHR; ++q) t += part[q];
                    p.nValid[0] = N - t;
                }
            }
        }
    }
    grid.sync();

    // ---------------- Phase 3: masks (one wave per row, grid-stride) --------
    for (int i = gwave; i < N; i += nWaves) {
        if (p.keySorted[i] == ninf) continue;     // invalid rows never read
        const float* bs = p.boxesSorted;
        float ax1 = bs[i*4+0], ay1 = bs[i*4+1], ax2 = bs[i*4+2], ay2 = bs[i*4+3];
        float aa  = p.areaSorted[i];
        int w0 = i >> 6;
#pragma unroll
        for (int k = 1; k <= 3; ++k) {
            unsigned long long bm = 0ULL;
            if (w0 - k >= 0) {
                int j = (w0 - k) * 64 + lane;     // j < i always
                float bx1 = bs[j*4+0], by1 = bs[j*4+1], bx2 = bs[j*4+2], by2 = bs[j*4+3];
                float ba  = p.areaSorted[j];
                float ix1 = fmaxf(ax1,bx1), iy1 = fmaxf(ay1,by1);
                float ix2 = fminf(ax2,bx2), iy2 = fminf(ay2,by2);
                float iw = fmaxf(fsub(ix2,ix1), 0.0f);
                float ih = fmaxf(fsub(iy2,iy1), 0.0f);
                float inter = fmul(iw, ih);
                float denom = fadd(fsub(fadd(aa, ba), inter), 1e-9f);
                float iou = inter / denom;
                bm = __ballot(iou > NMS_THR);
            }
            if (lane == 0) p.bq[(size_t)i*4 + k] = bm;
        }
        for (int w = w0; w < W; ++w) {
            int j = w*64 + lane;
            int bit = 0;
            if (j < N && j != i) {
                float bx1 = bs[j*4+0], by1 = bs[j*4+1], bx2 = bs[j*4+2], by2 = bs[j*4+3];
                float ba  = p.areaSorted[j];
                float ix1 = fmaxf(ax1,bx1), iy1 = fmaxf(ay1,by1);
                float ix2 = fminf(ax2,bx2), iy2 = fminf(ay2,by2);
                float iw = fmaxf(fsub(ix2,ix1), 0.0f);
                float ih = fmaxf(fsub(iy2,iy1), 0.0f);
                float inter = fmul(iw, ih);
                float denom = fadd(fsub(fadd(aa, ba), inter), 1e-9f);
                float iou = inter / denom;
                bit = (iou > NMS_THR) ? 1 : 0;
            }
            unsigned long long fwd = __ballot(bit && (j > i));
            if (w == w0) {
                unsigned long long bwd = __ballot(bit && (j < i));
                if (lane == 0) {
                    p.mask[(long)i*Wpad + w] = fwd;
                    p.bq[(size_t)i*4 + 0] = bwd;
                }
            } else {
                if (lane == 0) p.mask[(long)i*Wpad + w] = fwd;
            }
        }
    }
    grid.sync();

    // ---------------- Phase 4: greedy scan (block 0 only; R17 body) ---------
    if (bid == 0) {
        __shared__ unsigned long long ldsPartA[NACC+1];
        __shared__ unsigned long long ldsPartB[NACC+1];
        __shared__ unsigned long long ldsKeepLo, ldsKeepHi;
        const unsigned long long* mask = p.mask;
        const unsigned long long* bq   = p.bq;
        int* keepSorted = p.keepSorted;
        for (int i = tid; i < N; i += NTHR) keepSorted[i] = 0;
        if (tid <= NACC) { ldsPartA[tid] = 0ULL; ldsPartB[tid] = 0ULL; }
        if (tid == 0) { ldsKeepLo = 0ULL; ldsKeepHi = 0ULL; }
        __syncthreads();

        int nValid  = __builtin_amdgcn_readfirstlane(p.nValid[0]);
        int nChunks = (nValid + 127) >> 7;

        unsigned long long a0=0,a1=0,a2=0,a3=0, b0=0,b1=0,b2=0,b3=0;
        unsigned long long keepLoPrev = 0ULL, keepHiPrev = 0ULL;
        if (wi == 0 && nChunks > 0) {
            int rA = lane, rB = 64 + lane;
            if (rA < N) {
                ulonglong2 q01 = *(const ulonglong2*)(bq + (size_t)rA*4);
                ulonglong2 q23 = *(const ulonglong2*)(bq + (size_t)rA*4 + 2);
                a0=q01.x; a1=q01.y; a2=q23.x; a3=q23.y;
            }
            if (rB < N) {
                ulonglong2 q01 = *(const ulonglong2*)(bq + (size_t)rB*4);
                ulonglong2 q23 = *(const ulonglong2*)(bq + (size_t)rB*4 + 2);
                b0=q01.x; b1=q01.y; b2=q23.x; b3=q23.y;
            }
        }
        unsigned long long accx = 0ULL, accy = 0ULL;
        bool accWave = (wi >= 1);
        int  accIdx  = wi - 1;
        bool laneok  = (2*lane + 1 < Wpad);

        for (int c = 0; c < nChunks; ++c) {
            int base = c << 7;
            if (wi == 0) {
                unsigned long long na0=0,na1=0,na2=0,na3=0, nb0=0,nb1=0,nb2=0,nb3=0;
                if (c + 1 < nChunks) {
                    int rA = base + 128 + lane, rB = base + 192 + lane;
                    if (rA < N) {
                        ulonglong2 q01 = *(const ulonglong2*)(bq + (size_t)rA*4);
                        ulonglong2 q23 = *(const ulonglong2*)(bq + (size_t)rA*4 + 2);
                        na0=q01.x; na1=q01.y; na2=q23.x; na3=q23.y;
                    }
                    if (rB < N) {
                        ulonglong2 q01 = *(const ulonglong2*)(bq + (size_t)rB*4);
                        ulonglong2 q23 = *(const ulonglong2*)(bq + (size_t)rB*4 + 2);
                        nb0=q01.x; nb1=q01.y; nb2=q23.x; nb3=q23.y;
                    }
                }

                unsigned long long pA = 0ULL, pB = 0ULL;
#pragma unroll
                for (int k = 1; k <= NACC; ++k) { pA |= ldsPartA[k]; pB |= ldsPartB[k]; }
                unsigned long long prevLo =
                    __ballot(((a1 & keepHiPrev) | (a2 & keepLoPrev)) != 0ULL);
                unsigned long long prevHi =
                    __ballot(((b2 & keepHiPrev) | (b3 & keepLoPrev)) != 0ULL);
                unsigned long long incLo = rfl64(pA) | prevLo;
                unsigned long long incHi = rfl64(pB) | prevHi;
                int nv  = nValid - base;
                unsigned long long validLo = (nv >= 64) ? ~0ULL : ((1ULL << nv) - 1ULL);
                int nv2 = nv - 64;
                unsigned long long validHi = (nv2 >= 64) ? ~0ULL
                                            : (nv2 <= 0 ? 0ULL : ((1ULL << nv2) - 1ULL));
                unsigned long long candLo = validLo & ~incLo;
                unsigned long long candHi = validHi & ~incHi;
                unsigned long long keepLo = 0ULL, keepHi = 0ULL;

                while (candLo) {
                    int f = __builtin_ctzll(candLo);
                    unsigned long long sup = __ballot(((a0 >> f) & 1ULL) != 0ULL);
                    unsigned long long b = 1ULL << f;
                    keepLo |= b;
                    candLo &= ~sup & ~b;
                }
                candHi &= ~__ballot((b1 & keepLo) != 0ULL);
                while (candHi) {
                    int f = __builtin_ctzll(candHi);
                    unsigned long long sup = __ballot(((b0 >> f) & 1ULL) != 0ULL);
                    unsigned long long b = 1ULL << f;
                    keepHi |= b;
                    candHi &= ~sup & ~b;
                }
                keepLoPrev = keepLo; keepHiPrev = keepHi;
                if (lane == 0) { ldsKeepLo = keepLo; ldsKeepHi = keepHi; }
                if (base + lane < N)
                    keepSorted[base + lane]      = (int)((keepLo >> lane) & 1ULL);
                if (base + 64 + lane < N)
                    keepSorted[base + 64 + lane] = (int)((keepHi >> lane) & 1ULL);
                a0=na0; a1=na1; a2=na2; a3=na3; b0=nb0; b1=nb1; b2=nb2; b3=nb3;
            }
            BAR_LDS();                             // barrier A
            unsigned long long kLo = ldsKeepLo;
            unsigned long long kHi = ldsKeepHi;
            if (accWave && laneok && lane == c + 1) {
                ldsPartA[wi] = accx;
                ldsPartB[wi] = accy;
            }
            BAR_LDS();                             // barrier B
            if (accWave && laneok) {
                unsigned int myb = (accIdx < 4)
                    ? (unsigned int)((kLo >> (16*accIdx)) & 0xFFFFULL)
                    : (unsigned int)((kHi >> (16*(accIdx-4))) & 0xFFFFULL);
                if (myb) {
                    const unsigned long long* mb =
                        mask + (size_t)(base + 16*accIdx) * Wpad + 2*lane;
                    unsigned int b = myb;
                    int q0 = __builtin_ctz(b); b &= b - 1;
                    int q1=-1,q2=-1,q3=-1,q4=-1,q5=-1,q6=-1,q7=-1;
                    if (b) { q1 = __builtin_ctz(b); b &= b - 1; }
                    if (b) { q2 = __builtin_ctz(b); b &= b - 1; }
                    if (b) { q3 = __builtin_ctz(b); b &= b - 1; }
                    if (b) { q4 = __builtin_ctz(b); b &= b - 1; }
                    if (b) { q5 = __builtin_ctz(b); b &= b - 1; }
                    if (b) { q6 = __builtin_ctz(b); b &= b - 1; }
                    if (b) { q7 = __builtin_ctz(b); b &= b - 1; }
                    ulonglong2 v0 = {0,0}, v1 = {0,0}, v2 = {0,0}, v3 = {0,0};
                    ulonglong2 v4 = {0,0}, v5 = {0,0}, v6 = {0,0}, v7 = {0,0};
                    v0 = *(const ulonglong2*)(mb + (size_t)q0 * Wpad);
                    if (q1 >= 0) v1 = *(const ulonglong2*)(mb + (size_t)q1 * Wpad);
                    if (q2 >= 0) v2 = *(const ulonglong2*)(mb + (size_t)q2 * Wpad);
                    if (q3 >= 0) v3 = *(const ulonglong2*)(mb + (size_t)q3 * Wpad);
                    if (q4 >= 0) v4 = *(const ulonglong2*)(mb + (size_t)q4 * Wpad);
                    if (q5 >= 0) v5 = *(const ulonglong2*)(mb + (size_t)q5 * Wpad);
                    if (q6 >= 0) v6 = *(const ulonglong2*)(mb + (size_t)q6 * Wpad);
                    if (q7 >= 0) v7 = *(const ulonglong2*)(mb + (size_t)q7 * Wpad);
                    accx |= ((v0.x|v1.x)|(v2.x|v3.x)) | ((v4.x|v5.x)|(v6.x|v7.x));
                    accy |= ((v0.y|v1.y)|(v2.y|v3.y)) | ((v4.y|v5.y)|(v6.y|v7.y));
                    while (b) {
                        int a = __builtin_ctz(b); b &= b - 1;
                        ulonglong2 v = *(const ulonglong2*)(mb + (size_t)a * Wpad);
                        accx |= v.x; accy |= v.y;
                    }
                }
            }
        }
    }
    grid.sync();

    // ---------------- Phase 5: masked outputs -------------------------------
    for (int n = bid * NTHR + tid; n < N; n += gridDim.x * NTHR) {
        int k = p.keepSorted[p.rank[n]];
        float m = (float)k;
        p.out[n*4+0] = p.boxes[n*4+0]*m;
        p.out[n*4+1] = p.boxes[n*4+1]*m;
        p.out[n*4+2] = p.boxes[n*4+2]*m;
        p.out[n*4+3] = p.boxes[n*4+3]*m;
        p.out[(long)N*4 + n] = p.score[n]*m;
        p.out[(long)N*5 + n] = (float)(p.cls[n] * k);
    }
}

extern "C" void kernel_launch(void* const* d_in, const int* in_sizes, int n_in,
                              void* d_out, int out_size, void* d_ws, size_t ws_size,
                              hipStream_t stream) {
    int N = in_sizes[0] / 4;
    int C = in_sizes[2] / N;
    int W = (N + 63) / 64;
    int Wpad = (W + 1) & ~1;

    char* ws = (char*)d_ws;
    size_t off = 0;
    Params p;
    p.prop = (const float*)d_in[0];
    p.reg  = (const float*)d_in[1];
    p.clss = (const float*)d_in[2];
    p.stds = (const float*)d_in[3];
    p.img  = (const int*)d_in[4];
    p.boxes       = (float*)(ws + off); off += (size_t)N*4*sizeof(float);
    p.key         = (float*)(ws + off); off += (size_t)N*sizeof(float);
    p.score       = (float*)(ws + off); off += (size_t)N*sizeof(float);
    p.cls         = (int*)  (ws + off); off += (size_t)N*sizeof(int);
    p.rank        = (int*)  (ws + off); off += (size_t)N*sizeof(int);
    p.boxesSorted = (float*)(ws + off); off += (size_t)N*4*sizeof(float);
    p.areaSorted  = (float*)(ws + off); off += (size_t)N*sizeof(float);
    p.keySorted   = (float*)(ws + off); off += (size_t)N*sizeof(float);
    p.keepSorted  = (int*)  (ws + off); off += (size_t)N*sizeof(int);
    p.nValid      = (int*)  (ws + off); off += sizeof(int);
    off = (off + 31) & ~(size_t)31;
    p.bq   = (unsigned long long*)(ws + off); off += (size_t)N * 4 * sizeof(unsigned long long);
    p.mask = (unsigned long long*)(ws + off); off += (size_t)N * Wpad * sizeof(unsigned long long);
    p.out  = (float*)d_out;
    p.N = N; p.C = C; p.W = W; p.Wpad = Wpad;
    p.rankBlocks = (N + 63) / 64;
    (void)ws_size; (void)out_size; (void)n_in;

    size_t smemBytes = (size_t)N * sizeof(float) + NTHR * sizeof(int);
    void* args[] = { &p };
    hipLaunchCooperativeKernel((void*)k_all, dim3(NBLK), dim3(NTHR),
                               args, (unsigned int)smemBytes, stream);
}

// Round 20
// 170.759 us; speedup vs baseline: 1.7440x; 1.7440x over previous
//
#include <hip/hip_runtime.h>
#include <math.h>

#define NMS_THR 0.3f
#define NACC 8   // accumulator waves in k_scan (block = (1+NACC)*64 threads)

__device__ __forceinline__ float fmul(float a, float b){ return __fmul_rn(a,b); }
__device__ __forceinline__ float fadd(float a, float b){ return __fadd_rn(a,b); }
__device__ __forceinline__ float fsub(float a, float b){ return __fsub_rn(a,b); }

// Raw barrier: LDS ordering only — does NOT drain vmcnt.
#define BAR_LDS() asm volatile("s_waitcnt lgkmcnt(0)\n\ts_barrier" ::: "memory")

__device__ __forceinline__ unsigned long long rfl64(unsigned long long x){
    unsigned int lo = (unsigned int)__builtin_amdgcn_readfirstlane((int)(unsigned int)x);
    unsigned int hi = (unsigned int)__builtin_amdgcn_readfirstlane((int)(unsigned int)(x >> 32));
    return ((unsigned long long)hi << 32) | lo;
}

// K1: per-row softmax max/sum + argmax + per-class regression decode.
__global__ __launch_bounds__(256) void k_decode(
    const float* __restrict__ prop, const float* __restrict__ reg,
    const float* __restrict__ clss, const float* __restrict__ stds,
    const int* __restrict__ imgsz,
    float* __restrict__ boxes, float* __restrict__ key,
    float* __restrict__ score, int* __restrict__ cls,
    int N, int C)
{
    int wid  = threadIdx.x >> 6;
    int lane = threadIdx.x & 63;
    int n = blockIdx.x * 4 + wid;
    if (n >= N) return;
    const float* row = clss + (long)n * C;
    float ninf = -__builtin_inff();
    float x0 = (lane < C)      ? row[lane]      : ninf;
    float x1 = (lane + 64 < C) ? row[lane + 64] : ninf;
    float m = fmaxf(x0, x1);
    for (int o = 32; o > 0; o >>= 1) m = fmaxf(m, __shfl_xor(m, o));
    float e0 = (lane < C)      ? expf(x0 - m) : 0.0f;
    float e1 = (lane + 64 < C) ? expf(x1 - m) : 0.0f;
    float s = e0 + e1;
    for (int o = 32; o > 0; o >>= 1) s += __shfl_xor(s, o);
    float bv; int bi;
    if (e0 >= e1) { bv = e0; bi = lane; } else { bv = e1; bi = lane + 64; }
    for (int o = 32; o > 0; o >>= 1) {
        float ov = __shfl_xor(bv, o);
        int   oi = __shfl_xor(bi, o);
        if (ov > bv || (ov == bv && oi < bi)) { bv = ov; bi = oi; }
    }
    if (lane == 0) {
        float sc = 1.0f / s;
        int   c  = bi;
        int   valid = (c != 0);
        float p0 = prop[n*4+0], p1 = prop[n*4+1], p2 = prop[n*4+2], p3 = prop[n*4+3];
        float w  = fsub(p2, p0), h = fsub(p3, p1);
        float cx = fadd(p0, fmul(0.5f, w));
        float cy = fadd(p1, fmul(0.5f, h));
        const float* rr = reg + (long)n * C * 4 + (long)c * 4;
        float t0 = fmul(rr[0], stds[0]);
        float t1 = fmul(rr[1], stds[1]);
        float t2 = fmul(rr[2], stds[2]);
        float t3 = fmul(rr[3], stds[3]);
        float px = fadd(cx, fmul(w, t0));
        float py = fadd(cy, fmul(h, t1));
        float pw = fmul(w, expf(t2));
        float ph = fmul(h, expf(t3));
        float hi = (float)(imgsz[0] - 1);
        float bx1 = fminf(fmaxf(fsub(px, fmul(0.5f, pw)), 0.0f), hi);
        float by1 = fminf(fmaxf(fsub(py, fmul(0.5f, ph)), 0.0f), hi);
        float bx2 = fminf(fmaxf(fadd(px, fmul(0.5f, pw)), 0.0f), hi);
        float by2 = fminf(fmaxf(fadd(py, fmul(0.5f, ph)), 0.0f), hi);
        boxes[n*4+0]=bx1; boxes[n*4+1]=by1; boxes[n*4+2]=bx2; boxes[n*4+3]=by2;
        score[n] = sc;
        cls[n]   = c;
        key[n]   = valid ? sc : ninf;
    }
}

// K2: stable descending rank sort + nValid.
__global__ __launch_bounds__(256) void k_rank(
    const float* __restrict__ key, const float* __restrict__ boxes,
    float* __restrict__ boxesSorted, float* __restrict__ areaSorted,
    float* __restrict__ keySorted, int* __restrict__ rank,
    int* __restrict__ nValidPtr, int N)
{
    extern __shared__ float lkey[];
    __shared__ int part[256];
    int tid = threadIdx.x;
    for (int j = tid; j < N; j += 256) lkey[j] = key[j];
    __syncthreads();

    int i = blockIdx.x * 64 + (tid & 63);
    int s = tid >> 6;
    int Q = (N + 3) >> 2;
    int r_part = 0;
    if (i < N) {
        float ki = lkey[i];
        int j0 = s * Q, j1 = min(N, j0 + Q);
        for (int j = j0; j < j1; ++j) {
            float kj = lkey[j];
            r_part += (kj > ki) || (kj == ki && j < i);
        }
    }
    part[tid] = r_part;
    __syncthreads();

    if (tid < 64 && i < N) {
        int r = part[tid] + part[tid+64] + part[tid+128] + part[tid+192];
        float ki = lkey[i];
        rank[i] = r;
        float b0 = boxes[i*4+0], b1 = boxes[i*4+1], b2 = boxes[i*4+2], b3 = boxes[i*4+3];
        boxesSorted[r*4+0]=b0; boxesSorted[r*4+1]=b1; boxesSorted[r*4+2]=b2; boxesSorted[r*4+3]=b3;
        areaSorted[r] = fmul(fsub(b2,b0), fsub(b3,b1));
        keySorted[r]  = ki;
    }

    if (blockIdx.x == 0) {
        __syncthreads();
        float ninf = -__builtin_inff();
        int inv = 0;
        for (int j = tid; j < N; j += 256) inv += (lkey[j] == ninf);
        part[tid] = inv;
        __syncthreads();
        if (tid == 0) {
            int t = 0;
            for (int q = 0; q < 256; ++q) t += part[q];
            nValidPtr[0] = N - t;
        }
    }
}

// K3: suppression bitmask, row-major padded (forward rows for acc waves), plus
// per-row BACKWARD quad bq[i*4+k]:
//   k=0: bits j<(i&63) in own word w0 with IoU>thr
//   k=1..3: bits j in word w0-k with IoU>thr (0 if w0-k < 0)
// (IoU symmetric; all j in these words are < i.)
__global__ __launch_bounds__(256) void k_mask(
    const float* __restrict__ bs, const float* __restrict__ areas,
    const float* __restrict__ keySorted, unsigned long long* __restrict__ mask,
    unsigned long long* __restrict__ bq,
    int N, int W, int Wpad)
{
    int wid  = threadIdx.x >> 6;
    int lane = threadIdx.x & 63;
    int i = blockIdx.x * 4 + wid;
    if (i >= N) return;
    if (keySorted[i] == -__builtin_inff()) return;   // invalid rows never read
    float ax1 = bs[i*4+0], ay1 = bs[i*4+1], ax2 = bs[i*4+2], ay2 = bs[i*4+3];
    float aa  = areas[i];
    int w0 = i >> 6;
    // backward words k=1..3
#pragma unroll
    for (int k = 1; k <= 3; ++k) {
        unsigned long long bm = 0ULL;
        if (w0 - k >= 0) {
            int j = (w0 - k) * 64 + lane;    // j < i always
            float bx1 = bs[j*4+0], by1 = bs[j*4+1], bx2 = bs[j*4+2], by2 = bs[j*4+3];
            float ba  = areas[j];
            float ix1 = fmaxf(ax1,bx1), iy1 = fmaxf(ay1,by1);
            float ix2 = fminf(ax2,bx2), iy2 = fminf(ay2,by2);
            float iw = fmaxf(fsub(ix2,ix1), 0.0f);
            float ih = fmaxf(fsub(iy2,iy1), 0.0f);
            float inter = fmul(iw, ih);
            float denom = fadd(fsub(fadd(aa, ba), inter), 1e-9f);
            float iou = inter / denom;
            bm = __ballot(iou > NMS_THR);
        }
        if (lane == 0) bq[(size_t)i*4 + k] = bm;
    }
    // forward words + own-word backward
    for (int w = w0; w < W; ++w) {
        int j = w*64 + lane;
        int bit = 0;
        if (j < N && j != i) {
            float bx1 = bs[j*4+0], by1 = bs[j*4+1], bx2 = bs[j*4+2], by2 = bs[j*4+3];
            float ba  = areas[j];
            float ix1 = fmaxf(ax1,bx1), iy1 = fmaxf(ay1,by1);
            float ix2 = fminf(ax2,bx2), iy2 = fminf(ay2,by2);
            float iw = fmaxf(fsub(ix2,ix1), 0.0f);
            float ih = fmaxf(fsub(iy2,iy1), 0.0f);
            float inter = fmul(iw, ih);
            float denom = fadd(fsub(fadd(aa, ba), inter), 1e-9f);
            float iou = inter / denom;
            bit = (iou > NMS_THR) ? 1 : 0;
        }
        unsigned long long fwd = __ballot(bit && (j > i));
        if (w == w0) {
            unsigned long long bwd = __ballot(bit && (j < i));
            if (lane == 0) {
                mask[(long)i*Wpad + w] = fwd;
                bq[(size_t)i*4 + 0] = bwd;
            }
        } else {
            if (lane == 0) mask[(long)i*Wpad + w] = fwd;
        }
    }
}

// K4: wave-specialized greedy scan, 128-row chunks. Resolver is all
// backward-mask ballots: keep chain = {ctz -> broadcast bit-test -> ballot ->
// andn2}; prev-chunk suppression = 2 ballots on bq1..bq3 vs prev keep words.
// ldsPart covers chunks <= c-2 (lag-1 acc publish). Acc waves identical to R12.
__global__ __launch_bounds__((NACC+1)*64, 1) void k_scan(
    const unsigned long long* __restrict__ mask,
    const unsigned long long* __restrict__ bq,
    const int* __restrict__ nValidPtr,
    int* __restrict__ keepSorted, int N, int W, int Wpad)
{
    __shared__ unsigned long long ldsPartA[NACC+1];
    __shared__ unsigned long long ldsPartB[NACC+1];
    __shared__ unsigned long long ldsKeepLo, ldsKeepHi;
    int tid  = threadIdx.x;
    int wid  = tid >> 6;
    int lane = tid & 63;
    for (int i = tid; i < N; i += (NACC+1)*64) keepSorted[i] = 0;
    if (tid <= NACC) { ldsPartA[tid] = 0ULL; ldsPartB[tid] = 0ULL; }
    if (tid == 0) { ldsKeepLo = 0ULL; ldsKeepHi = 0ULL; }
    __syncthreads();

    int nValid  = __builtin_amdgcn_readfirstlane(nValidPtr[0]);
    int nChunks = (nValid + 127) >> 7;

    // resolver state: backward quads for current chunk rows
    unsigned long long a0=0,a1=0,a2=0,a3=0, b0=0,b1=0,b2=0,b3=0;
    unsigned long long keepLoPrev = 0ULL, keepHiPrev = 0ULL;
    if (wid == 0 && nChunks > 0) {
        int rA = lane, rB = 64 + lane;
        if (rA < N) {
            ulonglong2 q01 = *(const ulonglong2*)(bq + (size_t)rA*4);
            ulonglong2 q23 = *(const ulonglong2*)(bq + (size_t)rA*4 + 2);
            a0=q01.x; a1=q01.y; a2=q23.x; a3=q23.y;
        }
        if (rB < N) {
            ulonglong2 q01 = *(const ulonglong2*)(bq + (size_t)rB*4);
            ulonglong2 q23 = *(const ulonglong2*)(bq + (size_t)rB*4 + 2);
            b0=q01.x; b1=q01.y; b2=q23.x; b3=q23.y;
        }
    }
    unsigned long long accx = 0ULL, accy = 0ULL;
    bool accWave = (wid >= 1);
    int  accIdx  = wid - 1;
    bool laneok  = (2*lane + 1 < Wpad);

    for (int c = 0; c < nChunks; ++c) {
        int base = c << 7;
        if (wid == 0) {
            // prefetch next chunk's quads (vmem stays in flight across BAR_LDS)
            unsigned long long na0=0,na1=0,na2=0,na3=0, nb0=0,nb1=0,nb2=0,nb3=0;
            if (c + 1 < nChunks) {
                int rA = base + 128 + lane, rB = base + 192 + lane;
                if (rA < N) {
                    ulonglong2 q01 = *(const ulonglong2*)(bq + (size_t)rA*4);
                    ulonglong2 q23 = *(const ulonglong2*)(bq + (size_t)rA*4 + 2);
                    na0=q01.x; na1=q01.y; na2=q23.x; na3=q23.y;
                }
                if (rB < N) {
                    ulonglong2 q01 = *(const ulonglong2*)(bq + (size_t)rB*4);
                    ulonglong2 q23 = *(const ulonglong2*)(bq + (size_t)rB*4 + 2);
                    nb0=q01.x; nb1=q01.y; nb2=q23.x; nb3=q23.y;
                }
            }

            // inc: acc partials (chunks <= c-2) + prev-chunk ballots (chunk c-1)
            unsigned long long pA = 0ULL, pB = 0ULL;
#pragma unroll
            for (int k = 1; k <= NACC; ++k) { pA |= ldsPartA[k]; pB |= ldsPartB[k]; }
            unsigned long long prevLo =
                __ballot(((a1 & keepHiPrev) | (a2 & keepLoPrev)) != 0ULL);
            unsigned long long prevHi =
                __ballot(((b2 & keepHiPrev) | (b3 & keepLoPrev)) != 0ULL);
            unsigned long long incLo = rfl64(pA) | prevLo;
            unsigned long long incHi = rfl64(pB) | prevHi;
            int nv  = nValid - base;
            unsigned long long validLo = (nv >= 64) ? ~0ULL : ((1ULL << nv) - 1ULL);
            int nv2 = nv - 64;
            unsigned long long validHi = (nv2 >= 64) ? ~0ULL
                                        : (nv2 <= 0 ? 0ULL : ((1ULL << nv2) - 1ULL));
            unsigned long long candLo = validLo & ~incLo;
            unsigned long long candHi = validHi & ~incHi;
            unsigned long long keepLo = 0ULL, keepHi = 0ULL;

            // phase 1: rows base..base+63 — broadcast-test chain
            while (candLo) {
                int f = __builtin_ctzll(candLo);
                unsigned long long sup = __ballot(((a0 >> f) & 1ULL) != 0ULL);
                unsigned long long b = 1ULL << f;
                keepLo |= b;
                candLo &= ~sup & ~b;
            }
            // phase-1 keeps suppress second half: one ballot (b1 = word 2c)
            candHi &= ~__ballot((b1 & keepLo) != 0ULL);
            // phase 2: rows base+64..base+127
            while (candHi) {
                int f = __builtin_ctzll(candHi);
                unsigned long long sup = __ballot(((b0 >> f) & 1ULL) != 0ULL);
                unsigned long long b = 1ULL << f;
                keepHi |= b;
                candHi &= ~sup & ~b;
            }
            keepLoPrev = keepLo; keepHiPrev = keepHi;
            if (lane == 0) { ldsKeepLo = keepLo; ldsKeepHi = keepHi; }
            if (base + lane < N)      keepSorted[base + lane]      = (int)((keepLo >> lane) & 1ULL);
            if (base + 64 + lane < N) keepSorted[base + 64 + lane] = (int)((keepHi >> lane) & 1ULL);
            a0=na0; a1=na1; a2=na2; a3=na3; b0=nb0; b1=nb1; b2=nb2; b3=nb3;
        }
        BAR_LDS();                             // barrier A
        unsigned long long kLo = ldsKeepLo;
        unsigned long long kHi = ldsKeepHi;
        if (accWave && laneok && lane == c + 1) {  // publish words 2c+2, 2c+3
            ldsPartA[wid] = accx;
            ldsPartB[wid] = accy;
        }
        BAR_LDS();                             // barrier B
        if (accWave && laneok) {
            unsigned int myb = (accIdx < 4)
                ? (unsigned int)((kLo >> (16*accIdx)) & 0xFFFFULL)
                : (unsigned int)((kHi >> (16*(accIdx-4))) & 0xFFFFULL);
            if (myb) {
                const unsigned long long* mb =
                    mask + (size_t)(base + 16*accIdx) * Wpad + 2*lane;
                unsigned int b = myb;
                int q0 = __builtin_ctz(b); b &= b - 1;
                int q1=-1,q2=-1,q3=-1,q4=-1,q5=-1,q6=-1,q7=-1;
                if (b) { q1 = __builtin_ctz(b); b &= b - 1; }
                if (b) { q2 = __builtin_ctz(b); b &= b - 1; }
                if (b) { q3 = __builtin_ctz(b); b &= b - 1; }
                if (b) { q4 = __builtin_ctz(b); b &= b - 1; }
                if (b) { q5 = __builtin_ctz(b); b &= b - 1; }
                if (b) { q6 = __builtin_ctz(b); b &= b - 1; }
                if (b) { q7 = __builtin_ctz(b); b &= b - 1; }
                ulonglong2 v0 = {0,0}, v1 = {0,0}, v2 = {0,0}, v3 = {0,0};
                ulonglong2 v4 = {0,0}, v5 = {0,0}, v6 = {0,0}, v7 = {0,0};
                v0 = *(const ulonglong2*)(mb + (size_t)q0 * Wpad);
                if (q1 >= 0) v1 = *(const ulonglong2*)(mb + (size_t)q1 * Wpad);
                if (q2 >= 0) v2 = *(const ulonglong2*)(mb + (size_t)q2 * Wpad);
                if (q3 >= 0) v3 = *(const ulonglong2*)(mb + (size_t)q3 * Wpad);
                if (q4 >= 0) v4 = *(const ulonglong2*)(mb + (size_t)q4 * Wpad);
                if (q5 >= 0) v5 = *(const ulonglong2*)(mb + (size_t)q5 * Wpad);
                if (q6 >= 0) v6 = *(const ulonglong2*)(mb + (size_t)q6 * Wpad);
                if (q7 >= 0) v7 = *(const ulonglong2*)(mb + (size_t)q7 * Wpad);
                accx |= ((v0.x|v1.x)|(v2.x|v3.x)) | ((v4.x|v5.x)|(v6.x|v7.x));
                accy |= ((v0.y|v1.y)|(v2.y|v3.y)) | ((v4.y|v5.y)|(v6.y|v7.y));
                while (b) {
                    int a = __builtin_ctz(b); b &= b - 1;
                    ulonglong2 v = *(const ulonglong2*)(mb + (size_t)a * Wpad);
                    accx |= v.x; accy |= v.y;
                }
            }
        }
    }
}

// K5: write outputs in original order: boxes*m, score*m, float(cls*keep).
__global__ __launch_bounds__(256) void k_out(
    const float* __restrict__ boxes, const float* __restrict__ score,
    const int* __restrict__ cls, const int* __restrict__ rank,
    const int* __restrict__ keepSorted,
    float* __restrict__ out, int N)
{
    int n = blockIdx.x * blockDim.x + threadIdx.x;
    if (n >= N) return;
    int k = keepSorted[rank[n]];
    float m = (float)k;
    out[n*4+0] = boxes[n*4+0]*m;
    out[n*4+1] = boxes[n*4+1]*m;
    out[n*4+2] = boxes[n*4+2]*m;
    out[n*4+3] = boxes[n*4+3]*m;
    out[(long)N*4 + n] = score[n]*m;
    out[(long)N*5 + n] = (float)(cls[n] * k);
}

extern "C" void kernel_launch(void* const* d_in, const int* in_sizes, int n_in,
                              void* d_out, int out_size, void* d_ws, size_t ws_size,
                              hipStream_t stream) {
    const float* prop = (const float*)d_in[0];
    const float* reg  = (const float*)d_in[1];
    const float* clss = (const float*)d_in[2];
    const float* stds = (const float*)d_in[3];
    const int*   img  = (const int*)d_in[4];

    int N = in_sizes[0] / 4;
    int C = in_sizes[2] / N;
    int W = (N + 63) / 64;
    int Wpad = (W + 1) & ~1;

    char* ws = (char*)d_ws;
    size_t off = 0;
    float* boxes       = (float*)(ws + off); off += (size_t)N*4*sizeof(float);
    float* key         = (float*)(ws + off); off += (size_t)N*sizeof(float);
    float* score       = (float*)(ws + off); off += (size_t)N*sizeof(float);
    int*   cls         = (int*)  (ws + off); off += (size_t)N*sizeof(int);
    int*   rank        = (int*)  (ws + off); off += (size_t)N*sizeof(int);
    float* boxesSorted = (float*)(ws + off); off += (size_t)N*4*sizeof(float);
    float* areaSorted  = (float*)(ws + off); off += (size_t)N*sizeof(float);
    float* keySorted   = (float*)(ws + off); off += (size_t)N*sizeof(float);
    int*   keepSorted  = (int*)  (ws + off); off += (size_t)N*sizeof(int);
    int*   nValid      = (int*)  (ws + off); off += sizeof(int);
    off = (off + 31) & ~(size_t)31;
    unsigned long long* bq    = (unsigned long long*)(ws + off);
    off += (size_t)N * 4 * sizeof(unsigned long long);
    unsigned long long* mask  = (unsigned long long*)(ws + off);
    off += (size_t)N * Wpad * sizeof(unsigned long long);
    (void)ws_size; (void)out_size; (void)n_in;

    int rowBlocks  = (N + 3) / 4;
    int thrBlocks  = (N + 255) / 256;
    int rankBlocks = (N + 63) / 64;

    k_decode<<<rowBlocks, 256, 0, stream>>>(prop, reg, clss, stds, img,
                                            boxes, key, score, cls, N, C);
    k_rank<<<rankBlocks, 256, (size_t)N*sizeof(float), stream>>>(key, boxes,
                                            boxesSorted, areaSorted, keySorted, rank, nValid, N);
    k_mask<<<rowBlocks, 256, 0, stream>>>(boxesSorted, areaSorted, keySorted,
                                          mask, bq, N, W, Wpad);
    k_scan<<<1, (NACC+1)*64, 0, stream>>>(mask, bq, nValid, keepSorted, N, W, Wpad);
    k_out<<<thrBlocks, 256, 0, stream>>>(boxes, score, cls, rank, keepSorted,
                                         (float*)d_out, N);
}